// Round 1
// baseline (1040.222 us; speedup 1.0000x reference)
//
#include <hip/hip_runtime.h>

#define D_DIM 768
#define F_DIM 16384
#define M_CONN 262144
#define N_ROWS 1024   // B*S = 2*512

// ---------------------------------------------------------------------------
// Kernel 1: transpose up_decoder [D, F] -> udT [F, D] so per-connection dot
// products read contiguous rows on both sides.
// ---------------------------------------------------------------------------
__global__ __launch_bounds__(1024) void transpose_kernel(const float* __restrict__ in,
                                                         float* __restrict__ out) {
    __shared__ float tile[64][65];  // +1 pad to kill bank conflicts
    const int tx = threadIdx.x, ty = threadIdx.y;
    const int x = blockIdx.x * 64 + tx;        // f index (col of in)
    const int y0 = blockIdx.y * 64;            // d base (row of in)
#pragma unroll
    for (int k = 0; k < 64; k += 16)
        tile[ty + k][tx] = in[(size_t)(y0 + ty + k) * F_DIM + x];
    __syncthreads();
    const int xo = blockIdx.y * 64 + tx;       // d index (col of out)
    const int yo = blockIdx.x * 64;            // f base (row of out)
#pragma unroll
    for (int k = 0; k < 64; k += 16)
        out[(size_t)(yo + ty + k) * D_DIM + xo] = tile[tx][ty + k];
}

// ---------------------------------------------------------------------------
// Kernel 2: values[m] = dot(down_encoder[i_m, :], udT[j_m, :]) over D=768.
// One wave (64 lanes) per connection; 3 x float4 per lane per operand.
// i_indices sorted -> consecutive waves hit the same down_encoder row (L1/L2).
// ---------------------------------------------------------------------------
__global__ __launch_bounds__(256) void values_kernel(const float* __restrict__ de,
                                                     const float* __restrict__ udT,
                                                     const int* __restrict__ i_idx,
                                                     const int* __restrict__ j_idx,
                                                     float* __restrict__ values) {
    const int wave = (blockIdx.x * blockDim.x + threadIdx.x) >> 6;
    const int lane = threadIdx.x & 63;
    const int i = i_idx[wave];
    const int j = j_idx[wave];
    const float4* a = (const float4*)(de + (size_t)i * D_DIM);
    const float4* b = (const float4*)(udT + (size_t)j * D_DIM);
    float sum = 0.f;
#pragma unroll
    for (int t = 0; t < 3; ++t) {
        float4 av = a[lane + t * 64];
        float4 bv = b[lane + t * 64];
        sum = fmaf(av.x, bv.x, sum);
        sum = fmaf(av.y, bv.y, sum);
        sum = fmaf(av.z, bv.z, sum);
        sum = fmaf(av.w, bv.w, sum);
    }
#pragma unroll
    for (int off = 32; off > 0; off >>= 1)
        sum += __shfl_down(sum, off, 64);
    if (lane == 0) values[wave] = sum;
}

// ---------------------------------------------------------------------------
// Kernel 3: per (b,s) row: out[row, i_m] += up_facts[row, j_m] * values[m].
// Row (64KB) and fp32 accumulator (64KB) both in LDS (128KB -> 1 block/CU).
// Each thread owns a CONTIGUOUS chunk of 256 connections; sorted i gives runs
// of equal i -> register-accumulate, flush once per run via LDS atomicAdd.
// ---------------------------------------------------------------------------
__global__ __launch_bounds__(1024) void scatter_kernel(const float* __restrict__ up_facts,
                                                       const int* __restrict__ i_idx,
                                                       const int* __restrict__ j_idx,
                                                       const float* __restrict__ vals,
                                                       float* __restrict__ out) {
    extern __shared__ float lds[];
    float* row = lds;            // F_DIM floats
    float* acc = lds + F_DIM;    // F_DIM floats
    const size_t rbase = (size_t)blockIdx.x * F_DIM;

    // Stage row, zero accumulator (coalesced float4).
    const float4* src = (const float4*)(up_facts + rbase);
    for (int t = threadIdx.x; t < F_DIM / 4; t += blockDim.x) {
        ((float4*)row)[t] = src[t];
        ((float4*)acc)[t] = make_float4(0.f, 0.f, 0.f, 0.f);
    }
    __syncthreads();

    constexpr int PER = M_CONN / 1024;  // 256, 16B-aligned chunk base
    const int base = threadIdx.x * PER;
    int cur_i = -1;
    float sum = 0.f;

    auto process = [&](int i, int j, float v) {
        float x = row[j];
        if (i != cur_i) {
            if (cur_i >= 0) atomicAdd(&acc[cur_i], sum);
            cur_i = i;
            sum = 0.f;
        }
        sum = fmaf(x, v, sum);
    };

    for (int k = 0; k < PER; k += 4) {
        int4 ii = *(const int4*)(i_idx + base + k);
        int4 jj = *(const int4*)(j_idx + base + k);
        float4 vv = *(const float4*)(vals + base + k);
        process(ii.x, jj.x, vv.x);
        process(ii.y, jj.y, vv.y);
        process(ii.z, jj.z, vv.z);
        process(ii.w, jj.w, vv.w);
    }
    if (cur_i >= 0) atomicAdd(&acc[cur_i], sum);
    __syncthreads();

    // Write the finished row (coalesced float4).
    for (int t = threadIdx.x; t < F_DIM / 4; t += blockDim.x)
        ((float4*)(out + rbase))[t] = ((float4*)acc)[t];
}

// ---------------------------------------------------------------------------
extern "C" void kernel_launch(void* const* d_in, const int* in_sizes, int n_in,
                              void* d_out, int out_size, void* d_ws, size_t ws_size,
                              hipStream_t stream) {
    const float* up_facts = (const float*)d_in[0];   // [B,S,F]
    const float* de       = (const float*)d_in[1];   // [F,D]
    const float* ud       = (const float*)d_in[2];   // [D,F]
    const int*   i_idx    = (const int*)d_in[3];     // [M] sorted
    const int*   j_idx    = (const int*)d_in[4];     // [M]
    float* out = (float*)d_out;

    // Scratch plan: udT (48MB) lives in d_out (dead before scatter writes it);
    // values (1MB) lives in d_ws.
    float* udT    = out;
    float* values = (float*)d_ws;

    // 1) transpose up_decoder
    transpose_kernel<<<dim3(F_DIM / 64, D_DIM / 64), dim3(64, 16), 0, stream>>>(ud, udT);

    // 2) per-connection values
    values_kernel<<<M_CONN / 4, 256, 0, stream>>>(de, udT, i_idx, j_idx, values);

    // 3) gather/scatter per row (128KB dynamic LDS)
    (void)hipFuncSetAttribute((const void*)scatter_kernel,
                              hipFuncAttributeMaxDynamicSharedMemorySize, 128 * 1024);
    scatter_kernel<<<N_ROWS, 1024, 128 * 1024, stream>>>(up_facts, i_idx, j_idx, values, out);
}

// Round 2
// 482.074 us; speedup vs baseline: 2.1578x; 2.1578x over previous
//
#include <hip/hip_runtime.h>

#define D_DIM 768
#define F_DIM 16384
#define M_CONN 262144
#define N_ROWS 1024   // B*S = 2*512

// ---------------------------------------------------------------------------
// Generic 64x64 tiled transpose: in [rows, cols] -> out [cols, rows].
// grid (cols/64, rows/64), block (64,16). All dims here are multiples of 64.
// ---------------------------------------------------------------------------
__global__ __launch_bounds__(1024) void transpose_kernel(const float* __restrict__ in,
                                                         float* __restrict__ out,
                                                         int rows, int cols) {
    __shared__ float tile[64][65];  // +1 pad: no bank conflicts
    const int tx = threadIdx.x, ty = threadIdx.y;
    const int x = blockIdx.x * 64 + tx;        // col of in
    const int y0 = blockIdx.y * 64;            // row base of in
#pragma unroll
    for (int k = 0; k < 64; k += 16)
        tile[ty + k][tx] = in[(size_t)(y0 + ty + k) * cols + x];
    __syncthreads();
    const int xo = blockIdx.y * 64 + tx;       // col of out (= row of in)
    const int yo = blockIdx.x * 64;            // row base of out (= col of in)
#pragma unroll
    for (int k = 0; k < 64; k += 16)
        out[(size_t)(yo + ty + k) * rows + xo] = tile[tx][ty + k];
}

// ---------------------------------------------------------------------------
// values[m] = dot(de[i_m, :], udT[j_m, :]) over D=768. One wave per 4
// consecutive m; sorted i (runs ~16) -> de row cached in registers across m.
// ---------------------------------------------------------------------------
__global__ __launch_bounds__(256) void values_kernel(const float* __restrict__ de,
                                                     const float* __restrict__ udT,
                                                     const int* __restrict__ i_idx,
                                                     const int* __restrict__ j_idx,
                                                     float* __restrict__ values) {
    const int wave = (blockIdx.x * blockDim.x + threadIdx.x) >> 6;
    const int lane = threadIdx.x & 63;
    const int mbase = wave * 4;
    int cur_i = -1;
    float4 a0, a1, a2;
#pragma unroll
    for (int t = 0; t < 4; ++t) {
        const int m = mbase + t;
        const int i = i_idx[m];
        const int j = j_idx[m];
        if (i != cur_i) {  // wave-uniform branch (i uniform across lanes)
            const float4* a = (const float4*)(de + (size_t)i * D_DIM);
            a0 = a[lane]; a1 = a[lane + 64]; a2 = a[lane + 128];
            cur_i = i;
        }
        const float4* b = (const float4*)(udT + (size_t)j * D_DIM);
        float4 b0 = b[lane], b1 = b[lane + 64], b2 = b[lane + 128];
        float s = 0.f;
        s = fmaf(a0.x, b0.x, s); s = fmaf(a0.y, b0.y, s);
        s = fmaf(a0.z, b0.z, s); s = fmaf(a0.w, b0.w, s);
        s = fmaf(a1.x, b1.x, s); s = fmaf(a1.y, b1.y, s);
        s = fmaf(a1.z, b1.z, s); s = fmaf(a1.w, b1.w, s);
        s = fmaf(a2.x, b2.x, s); s = fmaf(a2.y, b2.y, s);
        s = fmaf(a2.z, b2.z, s); s = fmaf(a2.w, b2.w, s);
#pragma unroll
        for (int off = 32; off > 0; off >>= 1)
            s += __shfl_down(s, off, 64);
        if (lane == 0) values[m] = s;
    }
}

// ---------------------------------------------------------------------------
// seg[i] = lower_bound(i_idx, M, i); seg[F] = M. CSR row pointers.
// ---------------------------------------------------------------------------
__global__ __launch_bounds__(256) void seg_kernel(const int* __restrict__ i_idx,
                                                  int* __restrict__ seg) {
    const int i = blockIdx.x * blockDim.x + threadIdx.x;
    if (i > F_DIM) return;
    if (i == F_DIM) { seg[i] = M_CONN; return; }
    int lo = 0, hi = M_CONN;
    while (lo < hi) {
        int mid = (lo + hi) >> 1;
        if (i_idx[mid] < i) lo = mid + 1; else hi = mid;
    }
    seg[i] = lo;
}

// ---------------------------------------------------------------------------
// SpMM scatter, transposed layout: outT[i, :] = sum_{m in seg(i)} v_m * upT[j_m, :].
// One block (256 thr, float4/thr = 1024 cols) per i. No atomics, one write per i.
// ---------------------------------------------------------------------------
__global__ __launch_bounds__(256) void spmm_kernel(const float* __restrict__ upT,
                                                   const int* __restrict__ j_idx,
                                                   const float* __restrict__ vals,
                                                   const int* __restrict__ seg,
                                                   float* __restrict__ outT) {
    const int i = blockIdx.x;
    const int t = threadIdx.x;
    const int ms = seg[i], me = seg[i + 1];
    float4 acc0 = make_float4(0.f, 0.f, 0.f, 0.f);
    float4 acc1 = make_float4(0.f, 0.f, 0.f, 0.f);
    int m = ms;
    for (; m + 1 < me; m += 2) {
        const int j0 = j_idx[m], j1 = j_idx[m + 1];
        const float v0 = vals[m], v1 = vals[m + 1];
        const float4 x0 = ((const float4*)(upT + (size_t)j0 * N_ROWS))[t];
        const float4 x1 = ((const float4*)(upT + (size_t)j1 * N_ROWS))[t];
        acc0.x = fmaf(v0, x0.x, acc0.x); acc0.y = fmaf(v0, x0.y, acc0.y);
        acc0.z = fmaf(v0, x0.z, acc0.z); acc0.w = fmaf(v0, x0.w, acc0.w);
        acc1.x = fmaf(v1, x1.x, acc1.x); acc1.y = fmaf(v1, x1.y, acc1.y);
        acc1.z = fmaf(v1, x1.z, acc1.z); acc1.w = fmaf(v1, x1.w, acc1.w);
    }
    if (m < me) {
        const int j0 = j_idx[m];
        const float v0 = vals[m];
        const float4 x0 = ((const float4*)(upT + (size_t)j0 * N_ROWS))[t];
        acc0.x = fmaf(v0, x0.x, acc0.x); acc0.y = fmaf(v0, x0.y, acc0.y);
        acc0.z = fmaf(v0, x0.z, acc0.z); acc0.w = fmaf(v0, x0.w, acc0.w);
    }
    acc0.x += acc1.x; acc0.y += acc1.y; acc0.z += acc1.z; acc0.w += acc1.w;
    ((float4*)(outT + (size_t)i * N_ROWS))[t] = acc0;
}

// ---------------------------------------------------------------------------
// Buffer plan (ws needs ~65.1 MB):
//   ws + 0        (64 MB): udT [F,D] (stages 1-2), then outT [F,1024] (stages 5-6)
//   ws + 64 MB    ( 1 MB): values [M]
//   ws + 65 MB    (64 KB): seg [F+1]
//   d_out         (64 MB): upT [F,1024] (stages 3-5), then final out (stage 6)
// ---------------------------------------------------------------------------
extern "C" void kernel_launch(void* const* d_in, const int* in_sizes, int n_in,
                              void* d_out, int out_size, void* d_ws, size_t ws_size,
                              hipStream_t stream) {
    const float* up_facts = (const float*)d_in[0];   // [1024, F]
    const float* de       = (const float*)d_in[1];   // [F, D]
    const float* ud       = (const float*)d_in[2];   // [D, F]
    const int*   i_idx    = (const int*)d_in[3];     // [M] sorted
    const int*   j_idx    = (const int*)d_in[4];     // [M]
    float* out = (float*)d_out;

    char* ws = (char*)d_ws;
    float* regionA = (float*)ws;                                // 64 MB
    float* values  = (float*)(ws + (size_t)64 * 1024 * 1024);   // 1 MB
    int*   seg     = (int*)  (ws + (size_t)65 * 1024 * 1024);   // 64 KB + 4
    float* udT  = regionA;   // [F, D] 48 MB
    float* outT = regionA;   // [F, 1024] 64 MB (udT dead by then)
    float* upT  = out;       // [F, 1024] 64 MB (out dead until stage 6)

    // 1) udT = ud^T
    transpose_kernel<<<dim3(F_DIM / 64, D_DIM / 64), dim3(64, 16), 0, stream>>>(
        ud, udT, D_DIM, F_DIM);
    // 2) values[m] = <de[i_m], udT[j_m]>
    values_kernel<<<(M_CONN / 4) * 64 / 256, 256, 0, stream>>>(de, udT, i_idx, j_idx, values);
    // 3) upT = up_facts^T
    transpose_kernel<<<dim3(F_DIM / 64, N_ROWS / 64), dim3(64, 16), 0, stream>>>(
        up_facts, upT, N_ROWS, F_DIM);
    // 4) CSR row pointers from sorted i
    seg_kernel<<<(F_DIM + 1 + 255) / 256, 256, 0, stream>>>(i_idx, seg);
    // 5) outT[i] = sum v * upT[j]
    spmm_kernel<<<F_DIM, 256, 0, stream>>>(upT, j_idx, values, seg, outT);
    // 6) out = outT^T
    transpose_kernel<<<dim3(N_ROWS / 64, F_DIM / 64), dim3(64, 16), 0, stream>>>(
        outT, out, F_DIM, N_ROWS);
}

// Round 3
// 349.233 us; speedup vs baseline: 2.9786x; 1.3804x over previous
//
#include <hip/hip_runtime.h>
#include <hip/hip_bf16.h>

#define D_DIM 768
#define F_DIM 16384
#define M_CONN 262144
#define N_ROWS 1024   // B*S = 2*512

__device__ __forceinline__ float bf2f(unsigned short u) {
    return __uint_as_float(((unsigned int)u) << 16);
}

// ---------------------------------------------------------------------------
// fp32 -> fp32 64x64 tiled transpose (used for the final outT -> out).
// ---------------------------------------------------------------------------
__global__ __launch_bounds__(1024) void transpose_kernel(const float* __restrict__ in,
                                                         float* __restrict__ out,
                                                         int rows, int cols) {
    __shared__ float tile[64][65];
    const int tx = threadIdx.x, ty = threadIdx.y;
    const int x = blockIdx.x * 64 + tx;
    const int y0 = blockIdx.y * 64;
#pragma unroll
    for (int k = 0; k < 64; k += 16)
        tile[ty + k][tx] = in[(size_t)(y0 + ty + k) * cols + x];
    __syncthreads();
    const int xo = blockIdx.y * 64 + tx;
    const int yo = blockIdx.x * 64;
#pragma unroll
    for (int k = 0; k < 64; k += 16)
        out[(size_t)(yo + ty + k) * rows + xo] = tile[tx][ty + k];
}

// ---------------------------------------------------------------------------
// fp32 -> bf16 64x64 tiled transpose (stages udT and upT at half the bytes).
// ---------------------------------------------------------------------------
__global__ __launch_bounds__(1024) void transpose_f2b_kernel(const float* __restrict__ in,
                                                             unsigned short* __restrict__ out,
                                                             int rows, int cols) {
    __shared__ float tile[64][65];
    const int tx = threadIdx.x, ty = threadIdx.y;
    const int x = blockIdx.x * 64 + tx;
    const int y0 = blockIdx.y * 64;
#pragma unroll
    for (int k = 0; k < 64; k += 16)
        tile[ty + k][tx] = in[(size_t)(y0 + ty + k) * cols + x];
    __syncthreads();
    const int xo = blockIdx.y * 64 + tx;
    const int yo = blockIdx.x * 64;
#pragma unroll
    for (int k = 0; k < 64; k += 16) {
        __hip_bfloat16 b = __float2bfloat16(tile[tx][ty + k]);  // RNE
        out[(size_t)(yo + ty + k) * rows + xo] = *(unsigned short*)&b;
    }
}

// ---------------------------------------------------------------------------
// values[m] = dot(de[i_m, :], udT[j_m, :]) over D=768, udT in bf16.
// One wave per 4 consecutive m; sorted i -> de row register-cached across m.
// ---------------------------------------------------------------------------
__global__ __launch_bounds__(256) void values_kernel(const float* __restrict__ de,
                                                     const unsigned short* __restrict__ udT,
                                                     const int* __restrict__ i_idx,
                                                     const int* __restrict__ j_idx,
                                                     float* __restrict__ values) {
    const int wave = (blockIdx.x * blockDim.x + threadIdx.x) >> 6;
    const int lane = threadIdx.x & 63;
    const int mbase = wave * 4;
    int cur_i = -1;
    float4 a0, a1, a2;
#pragma unroll
    for (int t = 0; t < 4; ++t) {
        const int m = mbase + t;
        const int i = i_idx[m];
        const int j = j_idx[m];
        if (i != cur_i) {  // wave-uniform (i uniform across lanes)
            const float4* a = (const float4*)(de + (size_t)i * D_DIM);
            a0 = a[lane]; a1 = a[lane + 64]; a2 = a[lane + 128];
            cur_i = i;
        }
        const ushort4* b = (const ushort4*)(udT + (size_t)j * D_DIM);
        ushort4 u0 = b[lane], u1 = b[lane + 64], u2 = b[lane + 128];
        float s = 0.f;
        s = fmaf(a0.x, bf2f(u0.x), s); s = fmaf(a0.y, bf2f(u0.y), s);
        s = fmaf(a0.z, bf2f(u0.z), s); s = fmaf(a0.w, bf2f(u0.w), s);
        s = fmaf(a1.x, bf2f(u1.x), s); s = fmaf(a1.y, bf2f(u1.y), s);
        s = fmaf(a1.z, bf2f(u1.z), s); s = fmaf(a1.w, bf2f(u1.w), s);
        s = fmaf(a2.x, bf2f(u2.x), s); s = fmaf(a2.y, bf2f(u2.y), s);
        s = fmaf(a2.z, bf2f(u2.z), s); s = fmaf(a2.w, bf2f(u2.w), s);
#pragma unroll
        for (int off = 32; off > 0; off >>= 1)
            s += __shfl_down(s, off, 64);
        if (lane == 0) values[m] = s;
    }
}

// ---------------------------------------------------------------------------
// seg[i] = lower_bound(i_idx, M, i); seg[F] = M.
// ---------------------------------------------------------------------------
__global__ __launch_bounds__(256) void seg_kernel(const int* __restrict__ i_idx,
                                                  int* __restrict__ seg) {
    const int i = blockIdx.x * blockDim.x + threadIdx.x;
    if (i > F_DIM) return;
    if (i == F_DIM) { seg[i] = M_CONN; return; }
    int lo = 0, hi = M_CONN;
    while (lo < hi) {
        int mid = (lo + hi) >> 1;
        if (i_idx[mid] < i) lo = mid + 1; else hi = mid;
    }
    seg[i] = lo;
}

// ---------------------------------------------------------------------------
// SpMM, transposed layout, bf16 rows: outT[i,:] = sum_m v_m * upT[j_m,:].
// One 256-thread block per i; 4 bf16 (8B) per thread per connection; fp32 acc.
// ---------------------------------------------------------------------------
__global__ __launch_bounds__(256) void spmm_kernel(const unsigned short* __restrict__ upT,
                                                   const int* __restrict__ j_idx,
                                                   const float* __restrict__ vals,
                                                   const int* __restrict__ seg,
                                                   float* __restrict__ outT) {
    const int i = blockIdx.x;
    const int t = threadIdx.x;
    const int ms = seg[i], me = seg[i + 1];
    float4 acc0 = make_float4(0.f, 0.f, 0.f, 0.f);
    float4 acc1 = make_float4(0.f, 0.f, 0.f, 0.f);
    int m = ms;
    for (; m + 1 < me; m += 2) {
        const int j0 = j_idx[m], j1 = j_idx[m + 1];
        const float v0 = vals[m], v1 = vals[m + 1];
        const ushort4 x0 = ((const ushort4*)(upT + (size_t)j0 * N_ROWS))[t];
        const ushort4 x1 = ((const ushort4*)(upT + (size_t)j1 * N_ROWS))[t];
        acc0.x = fmaf(v0, bf2f(x0.x), acc0.x); acc0.y = fmaf(v0, bf2f(x0.y), acc0.y);
        acc0.z = fmaf(v0, bf2f(x0.z), acc0.z); acc0.w = fmaf(v0, bf2f(x0.w), acc0.w);
        acc1.x = fmaf(v1, bf2f(x1.x), acc1.x); acc1.y = fmaf(v1, bf2f(x1.y), acc1.y);
        acc1.z = fmaf(v1, bf2f(x1.z), acc1.z); acc1.w = fmaf(v1, bf2f(x1.w), acc1.w);
    }
    if (m < me) {
        const int j0 = j_idx[m];
        const float v0 = vals[m];
        const ushort4 x0 = ((const ushort4*)(upT + (size_t)j0 * N_ROWS))[t];
        acc0.x = fmaf(v0, bf2f(x0.x), acc0.x); acc0.y = fmaf(v0, bf2f(x0.y), acc0.y);
        acc0.z = fmaf(v0, bf2f(x0.z), acc0.z); acc0.w = fmaf(v0, bf2f(x0.w), acc0.w);
    }
    acc0.x += acc1.x; acc0.y += acc1.y; acc0.z += acc1.z; acc0.w += acc1.w;
    ((float4*)(outT + (size_t)i * N_ROWS))[t] = acc0;
}

// ---------------------------------------------------------------------------
// Buffer plan (ws ~65.1 MB, proven available in R2):
//   ws + 0     : udT bf16 [F,D] 24 MB (stages 1-2), then outT fp32 [F,1024] 64 MB
//   ws + 64 MB : values [M] fp32, 1 MB
//   ws + 65 MB : seg [F+1] int, 64 KB
//   d_out      : upT bf16 [F,1024] 32 MB (stages 3-5), then final out fp32
// ---------------------------------------------------------------------------
extern "C" void kernel_launch(void* const* d_in, const int* in_sizes, int n_in,
                              void* d_out, int out_size, void* d_ws, size_t ws_size,
                              hipStream_t stream) {
    const float* up_facts = (const float*)d_in[0];   // [1024, F]
    const float* de       = (const float*)d_in[1];   // [F, D]
    const float* ud       = (const float*)d_in[2];   // [D, F]
    const int*   i_idx    = (const int*)d_in[3];     // [M] sorted
    const int*   j_idx    = (const int*)d_in[4];     // [M]
    float* out = (float*)d_out;

    char* ws = (char*)d_ws;
    unsigned short* udT = (unsigned short*)ws;                     // bf16 [F, D]
    float* outT   = (float*)ws;                                    // fp32 [F, 1024] (udT dead)
    float* values = (float*)(ws + (size_t)64 * 1024 * 1024);       // 1 MB
    int*   seg    = (int*)  (ws + (size_t)65 * 1024 * 1024);       // 64 KB + 4
    unsigned short* upT = (unsigned short*)out;                    // bf16 [F, 1024]

    // 1) udT = bf16(ud^T)
    transpose_f2b_kernel<<<dim3(F_DIM / 64, D_DIM / 64), dim3(64, 16), 0, stream>>>(
        ud, udT, D_DIM, F_DIM);
    // 2) values[m] = <de[i_m], udT[j_m]>
    values_kernel<<<(M_CONN / 4) * 64 / 256, 256, 0, stream>>>(de, udT, i_idx, j_idx, values);
    // 3) upT = bf16(up_facts^T)
    transpose_f2b_kernel<<<dim3(F_DIM / 64, N_ROWS / 64), dim3(64, 16), 0, stream>>>(
        up_facts, upT, N_ROWS, F_DIM);
    // 4) CSR row pointers
    seg_kernel<<<(F_DIM + 1 + 255) / 256, 256, 0, stream>>>(i_idx, seg);
    // 5) outT[i] = sum v * upT[j]
    spmm_kernel<<<F_DIM, 256, 0, stream>>>(upT, j_idx, values, seg, outT);
    // 6) out = outT^T
    transpose_kernel<<<dim3(N_ROWS / 64, F_DIM / 64), dim3(64, 16), 0, stream>>>(
        outT, out, F_DIM, N_ROWS);
}